// Round 8
// baseline (6913.618 us; speedup 1.0000x reference)
//
#include <hip/hip_runtime.h>
#include <hip/hip_bf16.h>

// Problem dims (fixed)
#define B_ 32
#define S_ 64
#define H_ 512
#define T_ 32
#define V_ 32000

typedef __attribute__((ext_vector_type(8))) short bf16x8;
typedef __attribute__((ext_vector_type(4))) float f32x4;

static __device__ __forceinline__ unsigned short f2bf(float f) {
    unsigned int u = __float_as_uint(f);
    u += 0x7FFF + ((u >> 16) & 1);   // RNE
    return (unsigned short)(u >> 16);
}
static __device__ __forceinline__ float dot4(float4 a, float4 b) {
    return a.x * b.x + a.y * b.y + a.z * b.z + a.w * b.w;
}
static __device__ __forceinline__ float tanh_fast(float x) {
    x = fminf(fmaxf(x, -15.f), 15.f);
    float e = __expf(2.f * x);
    return (e - 1.f) / (e + 1.f);
}
static __device__ __forceinline__ float sigmoid_fast(float x) {
    return 1.f / (1.f + __expf(-x));
}

// ---------------------------------------------------------------------------
// One 128x128 output tile of C[m,n] = sum_{k in [k0beg,k0end)} A[m,k]*B[n,k]
// (+bias if non-null). Body identical to the r0-verified gemm_bt. (verified r7)
// ---------------------------------------------------------------------------
static __device__ __forceinline__ void gemm_tile_f32(
    const float* __restrict__ A, int Ald,
    const float* __restrict__ Bm, int Bld,
    const float* __restrict__ bias,
    float* __restrict__ C, int Cld,
    int m0, int n0, int k0beg, int k0end)
{
    __shared__ unsigned short As[128 * 32];
    __shared__ unsigned short Bs[128 * 32];

    const int tid  = threadIdx.x;
    const int lane = tid & 63;
    const int wave = tid >> 6;
    const int wm   = (wave & 1) * 64;
    const int wn   = (wave >> 1) * 64;
    const int quad = lane >> 4;   // 0..3
    const int l16  = lane & 15;

    f32x4 acc[4][4];
#pragma unroll
    for (int i = 0; i < 4; i++)
#pragma unroll
        for (int j = 0; j < 4; j++) acc[i][j] = (f32x4){0.f, 0.f, 0.f, 0.f};

    const int r0 = tid >> 2;  // 0..63 (row group)
    const int q4 = tid & 3;   // 0..3  (k sub-chunk of 8)

    for (int k0 = k0beg; k0 < k0end; k0 += 32) {
        __syncthreads();
#pragma unroll
        for (int rr = 0; rr < 2; rr++) {
            const int row = r0 + rr * 64;
            const float4 s0 = *(const float4*)(A + (size_t)(m0 + row) * Ald + k0 + q4 * 8);
            const float4 s1 = *(const float4*)(A + (size_t)(m0 + row) * Ald + k0 + q4 * 8 + 4);
            unsigned short tmp[8] = {f2bf(s0.x), f2bf(s0.y), f2bf(s0.z), f2bf(s0.w),
                                     f2bf(s1.x), f2bf(s1.y), f2bf(s1.z), f2bf(s1.w)};
            *(uint4*)(&As[row * 32 + q4 * 8]) = *(uint4*)tmp;
            const float4 t0 = *(const float4*)(Bm + (size_t)(n0 + row) * Bld + k0 + q4 * 8);
            const float4 t1 = *(const float4*)(Bm + (size_t)(n0 + row) * Bld + k0 + q4 * 8 + 4);
            unsigned short tb[8] = {f2bf(t0.x), f2bf(t0.y), f2bf(t0.z), f2bf(t0.w),
                                    f2bf(t1.x), f2bf(t1.y), f2bf(t1.z), f2bf(t1.w)};
            *(uint4*)(&Bs[row * 32 + q4 * 8]) = *(uint4*)tb;
        }
        __syncthreads();

        bf16x8 af[4], bfr[4];
#pragma unroll
        for (int i = 0; i < 4; i++)
            af[i] = *(const bf16x8*)(&As[(wm + 16 * i + l16) * 32 + quad * 8]);
#pragma unroll
        for (int j = 0; j < 4; j++)
            bfr[j] = *(const bf16x8*)(&Bs[(wn + 16 * j + l16) * 32 + quad * 8]);
#pragma unroll
        for (int i = 0; i < 4; i++)
#pragma unroll
            for (int j = 0; j < 4; j++)
                acc[i][j] = __builtin_amdgcn_mfma_f32_16x16x32_bf16(af[i], bfr[j], acc[i][j], 0, 0, 0);
    }

#pragma unroll
    for (int i = 0; i < 4; i++)
#pragma unroll
        for (int j = 0; j < 4; j++)
#pragma unroll
            for (int r = 0; r < 4; r++) {
                const int m = m0 + wm + 16 * i + quad * 4 + r;
                const int n = n0 + wn + 16 * j + l16;
                C[(size_t)m * Cld + n] = acc[i][j][r] + (bias ? bias[n] : 0.f);
            }
}

// ---------------------------------------------------------------------------
// Merged setup GEMM (verified r7): 608 blocks.
// ---------------------------------------------------------------------------
__global__ __launch_bounds__(256, 2)
void gemm_setup(const float* __restrict__ enc, const float* __restrict__ Xemb,
                const float* __restrict__ Ua_w, const float* __restrict__ W_ih,
                const float* __restrict__ b_ih,
                float* __restrict__ Pua, float* __restrict__ Gxe,
                float* __restrict__ Penc2)
{
    const int bid = blockIdx.x;
    if (bid < 128) {
        const int kk = bid & 1, l = bid >> 1;        // 64 tiles
        const int mt = l & 15, nt = l >> 4;          // 16 x 4
        gemm_tile_f32(enc, 1024, Ua_w, 1024, nullptr,
                      Pua + (size_t)kk * 1048576, 512,
                      mt * 128, nt * 128, kk * 512, kk * 512 + 512);
    } else if (bid < 224) {
        const int l = bid - 128;                     // 96 tiles
        const int mt = l & 7, nt = l >> 3;           // 8 x 12
        gemm_tile_f32(Xemb, 512, W_ih, 1536, b_ih,
                      Gxe, 1536, mt * 128, nt * 128, 0, 512);
    } else {
        int l = bid - 224;                           // 384 = 2 x 192 tiles
        const int kk = l & 1; l >>= 1;
        const int mt = l & 15, nt = l >> 4;          // 16 x 12
        gemm_tile_f32(enc, 1024, W_ih + 512, 1536, nullptr,
                      Penc2 + (size_t)kk * 3145728, 1536,
                      mt * 128, nt * 128, kk * 512, kk * 512 + 512);
    }
}

// Combine split-K partials (verified r7).
__global__ void k_combine(const float* __restrict__ Pua, const float* __restrict__ Ua_b,
                          float* __restrict__ ua, const float* __restrict__ Penc2,
                          float* __restrict__ ENC2)
{
    const int o = blockIdx.x * 256 + threadIdx.x;  // f4 units, 1,048,576 total
    if (o < 262144) {
        const float4 a = ((const float4*)Pua)[o];
        const float4 b = ((const float4*)Pua)[262144 + o];
        const float4 bi = *(const float4*)(Ua_b + (o & 127) * 4);
        float4 r; r.x = a.x + b.x + bi.x; r.y = a.y + b.y + bi.y;
        r.z = a.z + b.z + bi.z; r.w = a.w + b.w + bi.w;
        ((float4*)ua)[o] = r;
    } else {
        const int i = o - 262144;                   // 0..786431
        const float4 a = ((const float4*)Penc2)[i];
        const float4 b = ((const float4*)Penc2)[786432 + i];
        float4 r; r.x = a.x + b.x; r.y = a.y + b.y; r.z = a.z + b.z; r.w = a.w + b.w;
        ((float4*)ENC2)[i] = r;
    }
}

// ---------------------------------------------------------------------------
// Logits GEMM (verified r6): XCD-swizzled 1D grid; A bf16.
// ---------------------------------------------------------------------------
__global__ __launch_bounds__(256, 2)
void gemm_logits(const unsigned short* __restrict__ A16, const float* __restrict__ Bm,
                 const float* __restrict__ bias, float* __restrict__ C)
{
    const int bid = blockIdx.x;          // 0..2047
    const int xcd = bid & 7;
    const int l   = bid >> 3;            // 0..255
    const int nt  = (l >> 3) * 8 + xcd;  // 0..255
    if (nt >= 250) return;
    const int m0 = (l & 7) * 128;
    const int n0 = nt * 128;
    const int N = V_, K = 512, Bld = 512;

    __shared__ unsigned short As[128 * 32];
    __shared__ unsigned short Bs[128 * 32];

    const int tid  = threadIdx.x;
    const int lane = tid & 63;
    const int wave = tid >> 6;
    const int wm   = (wave & 1) * 64;
    const int wn   = (wave >> 1) * 64;
    const int quad = lane >> 4;
    const int l16  = lane & 15;

    f32x4 acc[4][4];
#pragma unroll
    for (int i = 0; i < 4; i++)
#pragma unroll
        for (int j = 0; j < 4; j++) acc[i][j] = (f32x4){0.f, 0.f, 0.f, 0.f};

    const int r0 = tid >> 2;
    const int q4 = tid & 3;

    for (int k0 = 0; k0 < K; k0 += 32) {
        __syncthreads();
#pragma unroll
        for (int rr = 0; rr < 2; rr++) {
            const int row = r0 + rr * 64;
            const uint4 v = *(const uint4*)(A16 + (size_t)(m0 + row) * K + k0 + q4 * 8);
            *(uint4*)(&As[row * 32 + q4 * 8]) = v;
            const float4 t0 = *(const float4*)(Bm + (size_t)(n0 + row) * Bld + k0 + q4 * 8);
            const float4 t1 = *(const float4*)(Bm + (size_t)(n0 + row) * Bld + k0 + q4 * 8 + 4);
            unsigned short tb[8] = {f2bf(t0.x), f2bf(t0.y), f2bf(t0.z), f2bf(t0.w),
                                    f2bf(t1.x), f2bf(t1.y), f2bf(t1.z), f2bf(t1.w)};
            *(uint4*)(&Bs[row * 32 + q4 * 8]) = *(uint4*)tb;
        }
        __syncthreads();

        bf16x8 af[4], bfr[4];
#pragma unroll
        for (int i = 0; i < 4; i++)
            af[i] = *(const bf16x8*)(&As[(wm + 16 * i + l16) * 32 + quad * 8]);
#pragma unroll
        for (int j = 0; j < 4; j++)
            bfr[j] = *(const bf16x8*)(&Bs[(wn + 16 * j + l16) * 32 + quad * 8]);
#pragma unroll
        for (int i = 0; i < 4; i++)
#pragma unroll
            for (int j = 0; j < 4; j++)
                acc[i][j] = __builtin_amdgcn_mfma_f32_16x16x32_bf16(af[i], bfr[j], acc[i][j], 0, 0, 0);
    }

#pragma unroll
    for (int i = 0; i < 4; i++)
#pragma unroll
        for (int j = 0; j < 4; j++)
#pragma unroll
            for (int r = 0; r < 4; r++) {
                const int m = m0 + wm + 16 * i + quad * 4 + r;
                const int n = n0 + wn + 16 * j + l16;
                C[(size_t)m * N + n] = acc[i][j][r] + bias[n];
            }
}

// ---------------------------------------------------------------------------
// setup kernels (verbatim r0)
// ---------------------------------------------------------------------------
__global__ void k_h0part(const float* __restrict__ ehid, const float* __restrict__ Wh,
                         float* __restrict__ h0p)
{
    const int o = blockIdx.x * 256 + threadIdx.x;  // 65536
    const int b = o & 31, j = (o >> 5) & 511, c = o >> 14;
    const float* x = ehid + b * 1024 + c * 256;
    const float* w = Wh + (size_t)j * 1024 + c * 256;
    float s = 0.f;
#pragma unroll 8
    for (int k = 0; k < 256; k += 4)
        s += dot4(*(const float4*)(x + k), *(const float4*)(w + k));
    h0p[c * 16384 + b * 512 + j] = s;
}

__global__ void k_h0fin(const float* __restrict__ h0p, const float* __restrict__ bh,
                        float* __restrict__ h)
{
    const int o = blockIdx.x * 256 + threadIdx.x;  // 16384
    h[o] = bh[o & 511] + h0p[o] + h0p[16384 + o] + h0p[32768 + o] + h0p[49152 + o];
}

__global__ void k_gather(const float* __restrict__ emb, const int* __restrict__ tgt,
                         float* __restrict__ Xemb)
{
    const int o = blockIdx.x * 256 + threadIdx.x;  // 131072
    const int r = o >> 7, k4 = (o & 127) * 4;
    const int b = r >> 5, t = r & 31;
    const int tok = t ? tgt[b * T_ + t - 1] : 0;
    *(float4*)(Xemb + (size_t)r * 512 + k4) = *(const float4*)(emb + (size_t)tok * 512 + k4);
}

// ---------------------------------------------------------------------------
// ONE launch per scan step: 32 blocks x 512 threads, block = batch b.
// All per-step data for b is computed block-locally:
//  1) q[512]  = Wa_w @ h_b + Wa_b   — wave-per-row, coalesced, shfl reduce
//     gh[1536]= W_hh @ h_b + b_hh   — same pattern
//  2) scores + softmax -> wsm (r6/r7-verified bodies)
//  3) gx[1536] = sum_s wsm[s]*ENC2[b,s,:] (r6-verified)
//  4) GRU finalize j=tid (r6-verified math) -> h, Hall, hf
// Kernel boundary = the h_t -> h_{t+1} sync. No cross-block dependency.
// ---------------------------------------------------------------------------
__global__ __launch_bounds__(512)
void k_step(float* __restrict__ h,
            const float* __restrict__ Wa_w, const float* __restrict__ Wa_b,
            const float* __restrict__ W_hh, const float* __restrict__ b_hh,
            const float* __restrict__ ua, const float* __restrict__ Va_w,
            const float* __restrict__ Va_b, const float* __restrict__ ENC2,
            const float* __restrict__ Gxe,
            unsigned short* __restrict__ Hall, float* __restrict__ attn_out,
            float* __restrict__ hf, int t)
{
    __shared__ float hs[512];
    __shared__ float qs[512];
    __shared__ float ghs[1536];
    __shared__ float gxs[1536];
    __shared__ float parts[64][8];
    __shared__ float wsm[64];

    const int b = blockIdx.x;
    const int tid = threadIdx.x;
    const int wv = tid >> 6;      // 0..7
    const int ln = tid & 63;      // lane

    hs[tid] = h[b * 512 + tid];
    __syncthreads();

    // each lane's 8 h-values, reused across all its rows
    const float4 ha = *(const float4*)(hs + ln * 8);
    const float4 hb = *(const float4*)(hs + ln * 8 + 4);

    // q: wave-per-row over Wa_w (64 rows per wave)
#pragma unroll 2
    for (int j = wv; j < 512; j += 8) {
        const float* wr = Wa_w + (size_t)j * 512 + ln * 8;
        float p = dot4(ha, *(const float4*)wr) + dot4(hb, *(const float4*)(wr + 4));
        for (int off = 32; off; off >>= 1) p += __shfl_down(p, off);
        if (ln == 0) qs[j] = p + Wa_b[j];
    }
    // gh: wave-per-row over W_hh (192 rows per wave)
#pragma unroll 2
    for (int r = wv; r < 1536; r += 8) {
        const float* wr = W_hh + (size_t)r * 512 + ln * 8;
        float p = dot4(ha, *(const float4*)wr) + dot4(hb, *(const float4*)(wr + 4));
        for (int off = 32; off; off >>= 1) p += __shfl_down(p, off);
        if (ln == 0) ghs[r] = p + b_hh[r];
    }
    __syncthreads();

    // scores: s = tid>>3 (64 rows), p = tid&7 (8 chunks of 64)  [r1/r7 layout]
    {
        const int s = tid >> 3, p = tid & 7;
        const float* uar = ua + ((size_t)(b * 64 + s)) * 512 + p * 64;
        const float* vp  = Va_w + p * 64;
        const float* qpp = qs + p * 64;
        float acc = 0.f;
#pragma unroll 4
        for (int k = 0; k < 64; k += 4) {
            const float4 u4 = *(const float4*)(uar + k);
            const float4 v4 = *(const float4*)(vp + k);
            const float4 q4 = *(const float4*)(qpp + k);
            acc += v4.x * tanh_fast(q4.x + u4.x) + v4.y * tanh_fast(q4.y + u4.y)
                 + v4.z * tanh_fast(q4.z + u4.z) + v4.w * tanh_fast(q4.w + u4.w);
        }
        parts[s][p] = acc;
    }
    __syncthreads();

    if (tid < 64) {
        float sc = parts[tid][0] + parts[tid][1] + parts[tid][2] + parts[tid][3]
                 + parts[tid][4] + parts[tid][5] + parts[tid][6] + parts[tid][7]
                 + Va_b[0];
        float mx = sc;
        for (int off = 32; off; off >>= 1) mx = fmaxf(mx, __shfl_down(mx, off));
        mx = __shfl(mx, 0);
        const float e = __expf(sc - mx);
        float sum = e;
        for (int off = 32; off; off >>= 1) sum += __shfl_down(sum, off);
        sum = __shfl(sum, 0);
        const float w = e / sum;
        wsm[tid] = w;
        attn_out[((size_t)b * T_ + t) * 64 + tid] = w;
    }
    __syncthreads();

    // gx = sum_s wsm[s] * ENC2[b,s,:]  (384 float4 columns)  [r6 body]
    if (tid < 384) {
        float4 a = {0.f, 0.f, 0.f, 0.f};
        const float* eb = ENC2 + ((size_t)b * 64) * 1536 + tid * 4;
        for (int s2 = 0; s2 < 64; s2++) {
            const float w = wsm[s2];
            const float4 e4 = *(const float4*)(eb + (size_t)s2 * 1536);
            a.x += w * e4.x; a.y += w * e4.y; a.z += w * e4.z; a.w += w * e4.w;
        }
        *(float4*)(&gxs[tid * 4]) = a;
    }
    __syncthreads();

    // GRU finalize, j = tid  [r6 math; gh already includes b_hh]
    {
        const int j = tid;
        const float gh0 = ghs[j], gh1 = ghs[512 + j], gh2 = ghs[1024 + j];
        const float* gxe = Gxe + ((size_t)(b * T_ + t)) * 1536;
        const float gx0 = gxs[j] + gxe[j];
        const float gx1 = gxs[512 + j] + gxe[512 + j];
        const float gx2 = gxs[1024 + j] + gxe[1024 + j];
        const float r = sigmoid_fast(gx0 + gh0);
        const float z = sigmoid_fast(gx1 + gh1);
        const float n = tanh_fast(gx2 + r * gh2);
        const float hn = (1.f - z) * n + z * hs[j];
        h[b * 512 + j] = hn;
        Hall[((size_t)b * T_ + t) * 512 + j] = f2bf(hn);
        if (t == T_ - 1) hf[b * 512 + j] = hn;
    }
}

// ---------------------------------------------------------------------------
// Online log_softmax over V=32000 per row, in place. (verbatim r0)
// ---------------------------------------------------------------------------
__global__ void k_logsoftmax(float* __restrict__ logits)
{
    __shared__ float rm[4], rs[4];
    const int row = blockIdx.x;
    float* p = logits + (size_t)row * V_;
    const int tid = threadIdx.x;

    float m = -1e30f, s = 0.f;
    for (int i = tid * 4; i < V_; i += 1024) {
        const float4 x = *(const float4*)(p + i);
        const float m4 = fmaxf(fmaxf(x.x, x.y), fmaxf(x.z, x.w));
        const float mn = fmaxf(m, m4);
        s = s * __expf(m - mn) + __expf(x.x - mn) + __expf(x.y - mn)
          + __expf(x.z - mn) + __expf(x.w - mn);
        m = mn;
    }
    for (int off = 32; off; off >>= 1) {
        const float m2 = __shfl_down(m, off), s2 = __shfl_down(s, off);
        const float mn = fmaxf(m, m2);
        s = s * __expf(m - mn) + s2 * __expf(m2 - mn);
        m = mn;
    }
    if ((tid & 63) == 0) { rm[tid >> 6] = m; rs[tid >> 6] = s; }
    __syncthreads();
    const float M = fmaxf(fmaxf(rm[0], rm[1]), fmaxf(rm[2], rm[3]));
    const float S = rs[0] * __expf(rm[0] - M) + rs[1] * __expf(rm[1] - M)
                  + rs[2] * __expf(rm[2] - M) + rs[3] * __expf(rm[3] - M);
    const float lse = M + __logf(S);

    for (int i = tid * 4; i < V_; i += 1024) {
        float4 x = *(const float4*)(p + i);
        x.x -= lse; x.y -= lse; x.z -= lse; x.w -= lse;
        *(float4*)(p + i) = x;
    }
}

// ---------------------------------------------------------------------------
extern "C" void kernel_launch(void* const* d_in, const int* in_sizes, int n_in,
                              void* d_out, int out_size, void* d_ws, size_t ws_size,
                              hipStream_t stream)
{
    const float* enc   = (const float*)d_in[0];   // [B,S,2H]
    const float* ehid  = (const float*)d_in[1];   // [1,B,2H]
    const int*   tgt   = (const int*)d_in[2];     // [B,T]
    const float* emb   = (const float*)d_in[3];   // [V,H]
    const float* Wa_w  = (const float*)d_in[4];   // [H,H]
    const float* Wa_b  = (const float*)d_in[5];
    const float* Ua_w  = (const float*)d_in[6];   // [H,2H]
    const float* Ua_b  = (const float*)d_in[7];
    const float* Va_w  = (const float*)d_in[8];   // [1,H]
    const float* Va_b  = (const float*)d_in[9];   // [1]
    const float* W_ih  = (const float*)d_in[10];  // [3H,3H]
    const float* b_ih  = (const float*)d_in[11];
    const float* W_hh  = (const float*)d_in[12];  // [3H,H]
    const float* b_hh  = (const float*)d_in[13];
    const float* Wh    = (const float*)d_in[14];  // [H,2H]
    const float* bh    = (const float*)d_in[15];
    const float* out_w = (const float*)d_in[16];  // [V,H]
    const float* out_b = (const float*)d_in[17];  // [V]

    float* outp = (float*)d_out;
    float* lp   = outp;                 // [B,T,V] = 32,768,000 floats
    float* hf   = outp + 32768000;      // [1,B,H]
    float* attn = outp + 32784384;      // [B,T,S]

    // Transient scratch inside the lp region (all dead before the logits GEMM
    // overwrites lp):
    float* Gxe   = lp;                  // 1,572,864  [B*T, 3H]  emb-part + b_ih
    float* Xemb  = lp + 1572864;        //   524,288  [B*T, H]
    float* ENC2  = lp + 2359296;        // 3,145,728  [B*S, 3H]  enc @ W_ihc^T
    float* h0p   = lp + 5505024;        //    65,536  setup-only
    float* Pua   = lp + 5570560;        // 2,097,152  ua split-K partials
    float* Penc2 = lp + 7667712;        // 6,291,456  ENC2 split-K partials

    // Persistent ws (same layout as verified r0)
    float* ws  = (float*)d_ws;
    float* h   = ws;                    // 16,384
    float* ua  = ws + 49152;            // 1,048,576  [B*S, H]
    unsigned short* Hall = (unsigned short*)(ws + 1097728);  // [B*T, H] bf16

    // ---- setup ----
    k_h0part<<<256, 256, 0, stream>>>(ehid, Wh, h0p);
    k_h0fin<<<64, 256, 0, stream>>>(h0p, bh, h);
    k_gather<<<512, 256, 0, stream>>>(emb, tgt, Xemb);
    gemm_setup<<<608, 256, 0, stream>>>(enc, Xemb, Ua_w, W_ih, b_ih,
                                        Pua, Gxe, Penc2);
    k_combine<<<4096, 256, 0, stream>>>(Pua, Ua_b, ua, Penc2, ENC2);

    // ---- sequential scan: ONE launch per step ----
    for (int t = 0; t < T_; t++) {
        k_step<<<32, 512, 0, stream>>>(h, Wa_w, Wa_b, W_hh, b_hh, ua, Va_w,
                                       Va_b, ENC2, Gxe, Hall, attn, hf, t);
    }

    // ---- logits + log_softmax ----
    gemm_logits<<<2048, 256, 0, stream>>>(Hall, out_w, out_b, lp);
    k_logsoftmax<<<1024, 256, 0, stream>>>(lp);
}

// Round 10
// 1626.570 us; speedup vs baseline: 4.2504x; 4.2504x over previous
//
#include <hip/hip_runtime.h>
#include <hip/hip_bf16.h>

// Problem dims (fixed)
#define B_ 32
#define S_ 64
#define H_ 512
#define T_ 32
#define V_ 32000

typedef __attribute__((ext_vector_type(8))) short bf16x8;
typedef __attribute__((ext_vector_type(4))) float f32x4;

static __device__ __forceinline__ unsigned short f2bf(float f) {
    unsigned int u = __float_as_uint(f);
    u += 0x7FFF + ((u >> 16) & 1);   // RNE
    return (unsigned short)(u >> 16);
}
static __device__ __forceinline__ float dot4(float4 a, float4 b) {
    return a.x * b.x + a.y * b.y + a.z * b.z + a.w * b.w;
}
static __device__ __forceinline__ float tanh_fast(float x) {
    x = fminf(fmaxf(x, -15.f), 15.f);
    float e = __expf(2.f * x);
    return (e - 1.f) / (e + 1.f);
}
static __device__ __forceinline__ float sigmoid_fast(float x) {
    return 1.f / (1.f + __expf(-x));
}

// ---------------------------------------------------------------------------
// One 128x128 output tile of C = A@B^T (+bias). r0-verified body; r7-verified
// as a device function inside gemm_setup.
// ---------------------------------------------------------------------------
static __device__ __forceinline__ void gemm_tile_f32(
    const float* __restrict__ A, int Ald,
    const float* __restrict__ Bm, int Bld,
    const float* __restrict__ bias,
    float* __restrict__ C, int Cld,
    int m0, int n0, int k0beg, int k0end)
{
    __shared__ unsigned short As[128 * 32];
    __shared__ unsigned short Bs[128 * 32];

    const int tid  = threadIdx.x;
    const int lane = tid & 63;
    const int wave = tid >> 6;
    const int wm   = (wave & 1) * 64;
    const int wn   = (wave >> 1) * 64;
    const int quad = lane >> 4;   // 0..3
    const int l16  = lane & 15;

    f32x4 acc[4][4];
#pragma unroll
    for (int i = 0; i < 4; i++)
#pragma unroll
        for (int j = 0; j < 4; j++) acc[i][j] = (f32x4){0.f, 0.f, 0.f, 0.f};

    const int r0 = tid >> 2;  // 0..63 (row group)
    const int q4 = tid & 3;   // 0..3  (k sub-chunk of 8)

    for (int k0 = k0beg; k0 < k0end; k0 += 32) {
        __syncthreads();
#pragma unroll
        for (int rr = 0; rr < 2; rr++) {
            const int row = r0 + rr * 64;
            const float4 s0 = *(const float4*)(A + (size_t)(m0 + row) * Ald + k0 + q4 * 8);
            const float4 s1 = *(const float4*)(A + (size_t)(m0 + row) * Ald + k0 + q4 * 8 + 4);
            unsigned short tmp[8] = {f2bf(s0.x), f2bf(s0.y), f2bf(s0.z), f2bf(s0.w),
                                     f2bf(s1.x), f2bf(s1.y), f2bf(s1.z), f2bf(s1.w)};
            *(uint4*)(&As[row * 32 + q4 * 8]) = *(uint4*)tmp;
            const float4 t0 = *(const float4*)(Bm + (size_t)(n0 + row) * Bld + k0 + q4 * 8);
            const float4 t1 = *(const float4*)(Bm + (size_t)(n0 + row) * Bld + k0 + q4 * 8 + 4);
            unsigned short tb[8] = {f2bf(t0.x), f2bf(t0.y), f2bf(t0.z), f2bf(t0.w),
                                    f2bf(t1.x), f2bf(t1.y), f2bf(t1.z), f2bf(t1.w)};
            *(uint4*)(&Bs[row * 32 + q4 * 8]) = *(uint4*)tb;
        }
        __syncthreads();

        bf16x8 af[4], bfr[4];
#pragma unroll
        for (int i = 0; i < 4; i++)
            af[i] = *(const bf16x8*)(&As[(wm + 16 * i + l16) * 32 + quad * 8]);
#pragma unroll
        for (int j = 0; j < 4; j++)
            bfr[j] = *(const bf16x8*)(&Bs[(wn + 16 * j + l16) * 32 + quad * 8]);
#pragma unroll
        for (int i = 0; i < 4; i++)
#pragma unroll
            for (int j = 0; j < 4; j++)
                acc[i][j] = __builtin_amdgcn_mfma_f32_16x16x32_bf16(af[i], bfr[j], acc[i][j], 0, 0, 0);
    }

#pragma unroll
    for (int i = 0; i < 4; i++)
#pragma unroll
        for (int j = 0; j < 4; j++)
#pragma unroll
            for (int r = 0; r < 4; r++) {
                const int m = m0 + wm + 16 * i + quad * 4 + r;
                const int n = n0 + wn + 16 * j + l16;
                C[(size_t)m * Cld + n] = acc[i][j][r] + (bias ? bias[n] : 0.f);
            }
}

// ---------------------------------------------------------------------------
// Merged setup GEMM (r7-verified): 608 blocks.
//  bid   0..127 : ua partials  (split-K x2, 16x4 tiles)   Pua[kk] = enc·Ua_w^T
//  bid 128..223 : Gxe (full K=512, 8x12 tiles, + b_ih)    Gxe = Xemb·W_ih[:,:512]^T
//  bid 224..607 : ENC2 partials (split-K x2, 16x12 tiles) Penc2[kk] = enc·W_ihc^T
// ---------------------------------------------------------------------------
__global__ __launch_bounds__(256, 2)
void gemm_setup(const float* __restrict__ enc, const float* __restrict__ Xemb,
                const float* __restrict__ Ua_w, const float* __restrict__ W_ih,
                const float* __restrict__ b_ih,
                float* __restrict__ Pua, float* __restrict__ Gxe,
                float* __restrict__ Penc2)
{
    const int bid = blockIdx.x;
    if (bid < 128) {
        const int kk = bid & 1, l = bid >> 1;        // 64 tiles
        const int mt = l & 15, nt = l >> 4;          // 16 x 4
        gemm_tile_f32(enc, 1024, Ua_w, 1024, nullptr,
                      Pua + (size_t)kk * 1048576, 512,
                      mt * 128, nt * 128, kk * 512, kk * 512 + 512);
    } else if (bid < 224) {
        const int l = bid - 128;                     // 96 tiles
        const int mt = l & 7, nt = l >> 3;           // 8 x 12
        gemm_tile_f32(Xemb, 512, W_ih, 1536, b_ih,
                      Gxe, 1536, mt * 128, nt * 128, 0, 512);
    } else {
        int l = bid - 224;                           // 384 = 2 x 192 tiles
        const int kk = l & 1; l >>= 1;
        const int mt = l & 15, nt = l >> 4;          // 16 x 12
        gemm_tile_f32(enc, 1024, W_ih + 512, 1536, nullptr,
                      Penc2 + (size_t)kk * 3145728, 1536,
                      mt * 128, nt * 128, kk * 512, kk * 512 + 512);
    }
}

// Combine split-K partials (r7-verified).
__global__ void k_combine(const float* __restrict__ Pua, const float* __restrict__ Ua_b,
                          float* __restrict__ ua, const float* __restrict__ Penc2,
                          float* __restrict__ ENC2)
{
    const int o = blockIdx.x * 256 + threadIdx.x;  // f4 units, 1,048,576 total
    if (o < 262144) {
        const float4 a = ((const float4*)Pua)[o];
        const float4 b = ((const float4*)Pua)[262144 + o];
        const float4 bi = *(const float4*)(Ua_b + (o & 127) * 4);
        float4 r; r.x = a.x + b.x + bi.x; r.y = a.y + b.y + bi.y;
        r.z = a.z + b.z + bi.z; r.w = a.w + b.w + bi.w;
        ((float4*)ua)[o] = r;
    } else {
        const int i = o - 262144;                   // 0..786431
        const float4 a = ((const float4*)Penc2)[i];
        const float4 b = ((const float4*)Penc2)[786432 + i];
        float4 r; r.x = a.x + b.x; r.y = a.y + b.y; r.z = a.z + b.z; r.w = a.w + b.w;
        ((float4*)ENC2)[i] = r;
    }
}

// ---------------------------------------------------------------------------
// Logits GEMM (r6-verified): XCD-swizzled 1D grid; A bf16.
// ---------------------------------------------------------------------------
__global__ __launch_bounds__(256, 2)
void gemm_logits(const unsigned short* __restrict__ A16, const float* __restrict__ Bm,
                 const float* __restrict__ bias, float* __restrict__ C)
{
    const int bid = blockIdx.x;          // 0..2047
    const int xcd = bid & 7;
    const int l   = bid >> 3;            // 0..255
    const int nt  = (l >> 3) * 8 + xcd;  // 0..255
    if (nt >= 250) return;
    const int m0 = (l & 7) * 128;
    const int n0 = nt * 128;
    const int N = V_, K = 512, Bld = 512;

    __shared__ unsigned short As[128 * 32];
    __shared__ unsigned short Bs[128 * 32];

    const int tid  = threadIdx.x;
    const int lane = tid & 63;
    const int wave = tid >> 6;
    const int wm   = (wave & 1) * 64;
    const int wn   = (wave >> 1) * 64;
    const int quad = lane >> 4;
    const int l16  = lane & 15;

    f32x4 acc[4][4];
#pragma unroll
    for (int i = 0; i < 4; i++)
#pragma unroll
        for (int j = 0; j < 4; j++) acc[i][j] = (f32x4){0.f, 0.f, 0.f, 0.f};

    const int r0 = tid >> 2;
    const int q4 = tid & 3;

    for (int k0 = 0; k0 < K; k0 += 32) {
        __syncthreads();
#pragma unroll
        for (int rr = 0; rr < 2; rr++) {
            const int row = r0 + rr * 64;
            const uint4 v = *(const uint4*)(A16 + (size_t)(m0 + row) * K + k0 + q4 * 8);
            *(uint4*)(&As[row * 32 + q4 * 8]) = v;
            const float4 t0 = *(const float4*)(Bm + (size_t)(n0 + row) * Bld + k0 + q4 * 8);
            const float4 t1 = *(const float4*)(Bm + (size_t)(n0 + row) * Bld + k0 + q4 * 8 + 4);
            unsigned short tb[8] = {f2bf(t0.x), f2bf(t0.y), f2bf(t0.z), f2bf(t0.w),
                                    f2bf(t1.x), f2bf(t1.y), f2bf(t1.z), f2bf(t1.w)};
            *(uint4*)(&Bs[row * 32 + q4 * 8]) = *(uint4*)tb;
        }
        __syncthreads();

        bf16x8 af[4], bfr[4];
#pragma unroll
        for (int i = 0; i < 4; i++)
            af[i] = *(const bf16x8*)(&As[(wm + 16 * i + l16) * 32 + quad * 8]);
#pragma unroll
        for (int j = 0; j < 4; j++)
            bfr[j] = *(const bf16x8*)(&Bs[(wn + 16 * j + l16) * 32 + quad * 8]);
#pragma unroll
        for (int i = 0; i < 4; i++)
#pragma unroll
            for (int j = 0; j < 4; j++)
                acc[i][j] = __builtin_amdgcn_mfma_f32_16x16x32_bf16(af[i], bfr[j], acc[i][j], 0, 0, 0);
    }

#pragma unroll
    for (int i = 0; i < 4; i++)
#pragma unroll
        for (int j = 0; j < 4; j++)
#pragma unroll
            for (int r = 0; r < 4; r++) {
                const int m = m0 + wm + 16 * i + quad * 4 + r;
                const int n = n0 + wn + 16 * j + l16;
                C[(size_t)m * N + n] = acc[i][j][r] + bias[n];
            }
}

// ---------------------------------------------------------------------------
// setup kernels (r0-verified)
// ---------------------------------------------------------------------------
__global__ void k_h0part(const float* __restrict__ ehid, const float* __restrict__ Wh,
                         float* __restrict__ h0p)
{
    const int o = blockIdx.x * 256 + threadIdx.x;  // 65536
    const int b = o & 31, j = (o >> 5) & 511, c = o >> 14;
    const float* x = ehid + b * 1024 + c * 256;
    const float* w = Wh + (size_t)j * 1024 + c * 256;
    float s = 0.f;
#pragma unroll 8
    for (int k = 0; k < 256; k += 4)
        s += dot4(*(const float4*)(x + k), *(const float4*)(w + k));
    h0p[c * 16384 + b * 512 + j] = s;
}

__global__ void k_h0fin(const float* __restrict__ h0p, const float* __restrict__ bh,
                        float* __restrict__ h)
{
    const int o = blockIdx.x * 256 + threadIdx.x;  // 16384
    h[o] = bh[o & 511] + h0p[o] + h0p[16384 + o] + h0p[32768 + o] + h0p[49152 + o];
}

__global__ void k_gather(const float* __restrict__ emb, const int* __restrict__ tgt,
                         float* __restrict__ Xemb)
{
    const int o = blockIdx.x * 256 + threadIdx.x;  // 131072
    const int r = o >> 7, k4 = (o & 127) * 4;
    const int b = r >> 5, t = r & 31;
    const int tok = t ? tgt[b * T_ + t - 1] : 0;
    *(float4*)(Xemb + (size_t)r * 512 + k4) = *(const float4*)(emb + (size_t)tok * 512 + k4);
}

// ---------------------------------------------------------------------------
// Scan launch 1 (r6-verified): 512 blocks x 256 threads.
//  blocks 0..255 : qp partials — r0 k_q layout (b-lane broadcast of Wa_w)
//  blocks 256..511: ghp partials — r0 k_ggx gh-half layout
// ---------------------------------------------------------------------------
__global__ __launch_bounds__(256)
void k_q_gh(const float* __restrict__ h, const float* __restrict__ Wa_w,
            const float* __restrict__ W_hh,
            float* __restrict__ qp, float* __restrict__ ghp)
{
    const int bid = blockIdx.x;
    const int tid = threadIdx.x;
    if (bid < 256) {
        const int o = bid * 256 + tid;                        // 0..65535
        const int b = o & 31, j = (o >> 5) & 511, c = o >> 14;
        const float* x = h + b * 512 + c * 128;
        const float* w = Wa_w + (size_t)j * 512 + c * 128;
        float s = 0.f;
#pragma unroll 8
        for (int k = 0; k < 128; k += 4)
            s += dot4(*(const float4*)(x + k), *(const float4*)(w + k));
        qp[c * 16384 + b * 512 + j] = s;
    } else {
        const int o = (bid - 256) * 256 + tid;                // 0..65535
        const int b = o & 31, j = (o >> 5) & 511, c = o >> 14;
        const float* x  = h + b * 512 + c * 128;
        const float* w0 = W_hh + (size_t)j * 512 + c * 128;
        const float* w1 = w0 + 512 * 512;
        const float* w2 = w1 + 512 * 512;
        float s0 = 0.f, s1 = 0.f, s2 = 0.f;
#pragma unroll 8
        for (int k = 0; k < 128; k += 4) {
            const float4 xv = *(const float4*)(x + k);
            s0 += dot4(xv, *(const float4*)(w0 + k));
            s1 += dot4(xv, *(const float4*)(w1 + k));
            s2 += dot4(xv, *(const float4*)(w2 + k));
        }
        const int ix = b * 512 + j;
        ghp[(c * 3 + 0) * 16384 + ix] = s0;
        ghp[(c * 3 + 1) * 16384 + ix] = s1;
        ghp[(c * 3 + 2) * 16384 + ix] = s2;
    }
}

// ---------------------------------------------------------------------------
// Scan launch 2 (r6-verified): 32 blocks x 256 threads, block = batch b.
// q-sum -> scores -> softmax -> gx over ENC2 -> GRU finalize.
// ---------------------------------------------------------------------------
__global__ __launch_bounds__(256)
void k_attn_fin(const float* __restrict__ qp, const float* __restrict__ Wa_b,
                const float* __restrict__ ua, const float* __restrict__ Va_w,
                const float* __restrict__ Va_b, const float* __restrict__ ENC2,
                const float* __restrict__ ghp, const float* __restrict__ Gxe,
                const float* __restrict__ b_hh, float* __restrict__ h,
                unsigned short* __restrict__ Hall, float* __restrict__ attn_out,
                float* __restrict__ hf, int t)
{
    __shared__ float qs[512];
    __shared__ float parts[64][4];
    __shared__ float wsm[64];
    __shared__ float gxs[1536];

    const int b = blockIdx.x;
    const int tid = threadIdx.x;

    for (int i = tid; i < 512; i += 256) {
        const int ix = b * 512 + i;
        qs[i] = qp[ix] + qp[16384 + ix] + qp[32768 + ix] + qp[49152 + ix] + Wa_b[i];
    }
    __syncthreads();

    {
        const int s = tid >> 2, p = tid & 3;
        const float* uar = ua + ((size_t)(b * 64 + s)) * 512 + p * 128;
        const float* vp = Va_w + p * 128;
        float acc = 0.f;
#pragma unroll 8
        for (int k = 0; k < 128; k += 4) {
            float4 u4 = *(const float4*)(uar + k);
            float4 v4 = *(const float4*)(vp + k);
            float4 q4 = *(const float4*)(&qs[p * 128 + k]);
            acc += v4.x * tanh_fast(q4.x + u4.x) + v4.y * tanh_fast(q4.y + u4.y)
                 + v4.z * tanh_fast(q4.z + u4.z) + v4.w * tanh_fast(q4.w + u4.w);
        }
        parts[s][p] = acc;
    }
    __syncthreads();

    if (tid < 64) {
        float sc = parts[tid][0] + parts[tid][1] + parts[tid][2] + parts[tid][3] + Va_b[0];
        float mx = sc;
        for (int off = 32; off; off >>= 1) mx = fmaxf(mx, __shfl_down(mx, off));
        mx = __shfl(mx, 0);
        float e = __expf(sc - mx);
        float sum = e;
        for (int off = 32; off; off >>= 1) sum += __shfl_down(sum, off);
        sum = __shfl(sum, 0);
        float w = e / sum;
        wsm[tid] = w;
        attn_out[((size_t)b * T_ + t) * 64 + tid] = w;
    }
    __syncthreads();

    for (int i4 = tid; i4 < 384; i4 += 256) {
        float4 a = {0.f, 0.f, 0.f, 0.f};
        const float* eb = ENC2 + ((size_t)b * 64) * 1536 + i4 * 4;
        for (int s2 = 0; s2 < 64; s2++) {
            const float w = wsm[s2];
            const float4 e4 = *(const float4*)(eb + (size_t)s2 * 1536);
            a.x += w * e4.x; a.y += w * e4.y; a.z += w * e4.z; a.w += w * e4.w;
        }
        *(float4*)(&gxs[i4 * 4]) = a;
    }
    __syncthreads();

    for (int j = tid; j < 512; j += 256) {
        const int o2 = b * 512 + j;
        float gh0 = b_hh[j], gh1 = b_hh[512 + j], gh2 = b_hh[1024 + j];
#pragma unroll
        for (int c2 = 0; c2 < 4; c2++) {
            gh0 += ghp[(c2 * 3 + 0) * 16384 + o2];
            gh1 += ghp[(c2 * 3 + 1) * 16384 + o2];
            gh2 += ghp[(c2 * 3 + 2) * 16384 + o2];
        }
        const float* gxe = Gxe + ((size_t)(b * T_ + t)) * 1536;
        const float gx0 = gxs[j] + gxe[j];
        const float gx1 = gxs[512 + j] + gxe[512 + j];
        const float gx2 = gxs[1024 + j] + gxe[1024 + j];
        const float r = sigmoid_fast(gx0 + gh0);
        const float z = sigmoid_fast(gx1 + gh1);
        const float n = tanh_fast(gx2 + r * gh2);
        const float hn = (1.f - z) * n + z * h[o2];
        h[o2] = hn;
        Hall[((size_t)b * T_ + t) * 512 + j] = f2bf(hn);
        if (t == T_ - 1) hf[o2] = hn;
    }
}

// ---------------------------------------------------------------------------
// Online log_softmax over V=32000 per row, in place. (r0-verified)
// ---------------------------------------------------------------------------
__global__ void k_logsoftmax(float* __restrict__ logits)
{
    __shared__ float rm[4], rs[4];
    const int row = blockIdx.x;
    float* p = logits + (size_t)row * V_;
    const int tid = threadIdx.x;

    float m = -1e30f, s = 0.f;
    for (int i = tid * 4; i < V_; i += 1024) {
        const float4 x = *(const float4*)(p + i);
        const float m4 = fmaxf(fmaxf(x.x, x.y), fmaxf(x.z, x.w));
        const float mn = fmaxf(m, m4);
        s = s * __expf(m - mn) + __expf(x.x - mn) + __expf(x.y - mn)
          + __expf(x.z - mn) + __expf(x.w - mn);
        m = mn;
    }
    for (int off = 32; off; off >>= 1) {
        const float m2 = __shfl_down(m, off), s2 = __shfl_down(s, off);
        const float mn = fmaxf(m, m2);
        s = s * __expf(m - mn) + s2 * __expf(m2 - mn);
        m = mn;
    }
    if ((tid & 63) == 0) { rm[tid >> 6] = m; rs[tid >> 6] = s; }
    __syncthreads();
    const float M = fmaxf(fmaxf(rm[0], rm[1]), fmaxf(rm[2], rm[3]));
    const float S = rs[0] * __expf(rm[0] - M) + rs[1] * __expf(rm[1] - M)
                  + rs[2] * __expf(rm[2] - M) + rs[3] * __expf(rm[3] - M);
    const float lse = M + __logf(S);

    for (int i = tid * 4; i < V_; i += 1024) {
        float4 x = *(const float4*)(p + i);
        x.x -= lse; x.y -= lse; x.z -= lse; x.w -= lse;
        *(float4*)(p + i) = x;
    }
}

// ---------------------------------------------------------------------------
extern "C" void kernel_launch(void* const* d_in, const int* in_sizes, int n_in,
                              void* d_out, int out_size, void* d_ws, size_t ws_size,
                              hipStream_t stream)
{
    const float* enc   = (const float*)d_in[0];   // [B,S,2H]
    const float* ehid  = (const float*)d_in[1];   // [1,B,2H]
    const int*   tgt   = (const int*)d_in[2];     // [B,T]
    const float* emb   = (const float*)d_in[3];   // [V,H]
    const float* Wa_w  = (const float*)d_in[4];   // [H,H]
    const float* Wa_b  = (const float*)d_in[5];
    const float* Ua_w  = (const float*)d_in[6];   // [H,2H]
    const float* Ua_b  = (const float*)d_in[7];
    const float* Va_w  = (const float*)d_in[8];   // [1,H]
    const float* Va_b  = (const float*)d_in[9];   // [1]
    const float* W_ih  = (const float*)d_in[10];  // [3H,3H]
    const float* b_ih  = (const float*)d_in[11];
    const float* W_hh  = (const float*)d_in[12];  // [3H,H]
    const float* b_hh  = (const float*)d_in[13];
    const float* Wh    = (const float*)d_in[14];  // [H,2H]
    const float* bh    = (const float*)d_in[15];
    const float* out_w = (const float*)d_in[16];  // [V,H]
    const float* out_b = (const float*)d_in[17];  // [V]

    float* outp = (float*)d_out;
    float* lp   = outp;                 // [B,T,V] = 32,768,000 floats
    float* hf   = outp + 32768000;      // [1,B,H]
    float* attn = outp + 32784384;      // [B,T,S]

    // Transient scratch inside the lp region (all dead before gemm_logits
    // overwrites lp):
    float* Gxe   = lp;                  // 1,572,864   [B*T, 3H]  emb-part + b_ih
    float* Xemb  = lp + 1572864;        //   524,288   [B*T, H]
    float* ghp   = lp + 2097152;        //   196,608   12 x [B*H]
    float* qp    = lp + 2293760;        //    65,536   4 x [B*H]
    float* ENC2  = lp + 2359296;        // 3,145,728   [B*S, 3H]  enc @ W_ihc^T
    float* h0p   = lp + 5505024;        //    65,536   setup-only
    float* Pua   = lp + 5570560;        // 2,097,152   ua split-K partials
    float* Penc2 = lp + 7667712;        // 6,291,456   ENC2 split-K partials

    // Persistent ws (same layout as verified r0)
    float* ws  = (float*)d_ws;
    float* h   = ws;                    // 16,384
    float* ua  = ws + 49152;            // 1,048,576  [B*S, H]
    unsigned short* Hall = (unsigned short*)(ws + 1097728);  // [B*T, H] bf16

    // ---- setup (r7-verified merged GEMM) ----
    k_h0part<<<256, 256, 0, stream>>>(ehid, Wh, h0p);
    k_h0fin<<<64, 256, 0, stream>>>(h0p, bh, h);
    k_gather<<<512, 256, 0, stream>>>(emb, tgt, Xemb);
    gemm_setup<<<608, 256, 0, stream>>>(enc, Xemb, Ua_w, W_ih, b_ih,
                                        Pua, Gxe, Penc2);
    k_combine<<<4096, 256, 0, stream>>>(Pua, Ua_b, ua, Penc2, ENC2);

    // ---- sequential scan: r6-verified 2-launch-per-step loop ----
    for (int t = 0; t < T_; t++) {
        k_q_gh<<<512, 256, 0, stream>>>(h, Wa_w, W_hh, qp, ghp);
        k_attn_fin<<<32, 256, 0, stream>>>(qp, Wa_b, ua, Va_w, Va_b, ENC2,
                                           ghp, Gxe, b_hh, h, Hall, attn,
                                           hf, t);
    }

    // ---- logits + log_softmax ----
    gemm_logits<<<2048, 256, 0, stream>>>(Hall, out_w, out_b, lp);
    k_logsoftmax<<<1024, 256, 0, stream>>>(lp);
}

// Round 11
// 1391.180 us; speedup vs baseline: 4.9696x; 1.1692x over previous
//
#include <hip/hip_runtime.h>
#include <hip/hip_bf16.h>

// Problem dims (fixed)
#define B_ 32
#define S_ 64
#define H_ 512
#define T_ 32
#define V_ 32000

typedef __attribute__((ext_vector_type(8))) short bf16x8;
typedef __attribute__((ext_vector_type(4))) float f32x4;

static __device__ __forceinline__ unsigned short f2bf(float f) {
    unsigned int u = __float_as_uint(f);
    u += 0x7FFF + ((u >> 16) & 1);   // RNE
    return (unsigned short)(u >> 16);
}
static __device__ __forceinline__ float dot4(float4 a, float4 b) {
    return a.x * b.x + a.y * b.y + a.z * b.z + a.w * b.w;
}
static __device__ __forceinline__ float tanh_fast(float x) {
    x = fminf(fmaxf(x, -15.f), 15.f);
    float e = __expf(2.f * x);
    return (e - 1.f) / (e + 1.f);
}
static __device__ __forceinline__ float sigmoid_fast(float x) {
    return 1.f / (1.f + __expf(-x));
}

// ---------------------------------------------------------------------------
// One 128x128 output tile of C = A@B^T (+bias). r0-verified body; r7-verified
// as a device function inside gemm_setup.
// ---------------------------------------------------------------------------
static __device__ __forceinline__ void gemm_tile_f32(
    const float* __restrict__ A, int Ald,
    const float* __restrict__ Bm, int Bld,
    const float* __restrict__ bias,
    float* __restrict__ C, int Cld,
    int m0, int n0, int k0beg, int k0end)
{
    __shared__ unsigned short As[128 * 32];
    __shared__ unsigned short Bs[128 * 32];

    const int tid  = threadIdx.x;
    const int lane = tid & 63;
    const int wave = tid >> 6;
    const int wm   = (wave & 1) * 64;
    const int wn   = (wave >> 1) * 64;
    const int quad = lane >> 4;   // 0..3
    const int l16  = lane & 15;

    f32x4 acc[4][4];
#pragma unroll
    for (int i = 0; i < 4; i++)
#pragma unroll
        for (int j = 0; j < 4; j++) acc[i][j] = (f32x4){0.f, 0.f, 0.f, 0.f};

    const int r0 = tid >> 2;  // 0..63 (row group)
    const int q4 = tid & 3;   // 0..3  (k sub-chunk of 8)

    for (int k0 = k0beg; k0 < k0end; k0 += 32) {
        __syncthreads();
#pragma unroll
        for (int rr = 0; rr < 2; rr++) {
            const int row = r0 + rr * 64;
            const float4 s0 = *(const float4*)(A + (size_t)(m0 + row) * Ald + k0 + q4 * 8);
            const float4 s1 = *(const float4*)(A + (size_t)(m0 + row) * Ald + k0 + q4 * 8 + 4);
            unsigned short tmp[8] = {f2bf(s0.x), f2bf(s0.y), f2bf(s0.z), f2bf(s0.w),
                                     f2bf(s1.x), f2bf(s1.y), f2bf(s1.z), f2bf(s1.w)};
            *(uint4*)(&As[row * 32 + q4 * 8]) = *(uint4*)tmp;
            const float4 t0 = *(const float4*)(Bm + (size_t)(n0 + row) * Bld + k0 + q4 * 8);
            const float4 t1 = *(const float4*)(Bm + (size_t)(n0 + row) * Bld + k0 + q4 * 8 + 4);
            unsigned short tb[8] = {f2bf(t0.x), f2bf(t0.y), f2bf(t0.z), f2bf(t0.w),
                                    f2bf(t1.x), f2bf(t1.y), f2bf(t1.z), f2bf(t1.w)};
            *(uint4*)(&Bs[row * 32 + q4 * 8]) = *(uint4*)tb;
        }
        __syncthreads();

        bf16x8 af[4], bfr[4];
#pragma unroll
        for (int i = 0; i < 4; i++)
            af[i] = *(const bf16x8*)(&As[(wm + 16 * i + l16) * 32 + quad * 8]);
#pragma unroll
        for (int j = 0; j < 4; j++)
            bfr[j] = *(const bf16x8*)(&Bs[(wn + 16 * j + l16) * 32 + quad * 8]);
#pragma unroll
        for (int i = 0; i < 4; i++)
#pragma unroll
            for (int j = 0; j < 4; j++)
                acc[i][j] = __builtin_amdgcn_mfma_f32_16x16x32_bf16(af[i], bfr[j], acc[i][j], 0, 0, 0);
    }

#pragma unroll
    for (int i = 0; i < 4; i++)
#pragma unroll
        for (int j = 0; j < 4; j++)
#pragma unroll
            for (int r = 0; r < 4; r++) {
                const int m = m0 + wm + 16 * i + quad * 4 + r;
                const int n = n0 + wn + 16 * j + l16;
                C[(size_t)m * Cld + n] = acc[i][j][r] + (bias ? bias[n] : 0.f);
            }
}

// ---------------------------------------------------------------------------
// Same tile, but the A matrix is the TEACHER-FORCED EMBEDDING: logical row
// r = b*T + t maps to emb[tok(b,t)] with tok = t ? tgt[b,t-1] : 0.
// Eliminates the k_gather pass + Xemb buffer. Body otherwise identical.
// ---------------------------------------------------------------------------
static __device__ __forceinline__ void gemm_tile_emb(
    const float* __restrict__ emb, const int* __restrict__ tgt,
    const float* __restrict__ Bm, int Bld,
    const float* __restrict__ bias,
    float* __restrict__ C, int Cld,
    int m0, int n0)
{
    __shared__ unsigned short As[128 * 32];
    __shared__ unsigned short Bs[128 * 32];

    const int tid  = threadIdx.x;
    const int lane = tid & 63;
    const int wave = tid >> 6;
    const int wm   = (wave & 1) * 64;
    const int wn   = (wave >> 1) * 64;
    const int quad = lane >> 4;   // 0..3
    const int l16  = lane & 15;

    f32x4 acc[4][4];
#pragma unroll
    for (int i = 0; i < 4; i++)
#pragma unroll
        for (int j = 0; j < 4; j++) acc[i][j] = (f32x4){0.f, 0.f, 0.f, 0.f};

    const int r0 = tid >> 2;  // 0..63 (row group)
    const int q4 = tid & 3;   // 0..3  (k sub-chunk of 8)

    // token ids for this thread's two rows (invariant over k0)
    int tok[2];
#pragma unroll
    for (int rr = 0; rr < 2; rr++) {
        const int r1 = m0 + r0 + rr * 64;          // logical row = b*T + t
        const int tt = r1 & 31, bb = r1 >> 5;
        tok[rr] = tt ? tgt[bb * T_ + tt - 1] : 0;
    }

    for (int k0 = 0; k0 < 512; k0 += 32) {
        __syncthreads();
#pragma unroll
        for (int rr = 0; rr < 2; rr++) {
            const int row = r0 + rr * 64;
            const float* arow = emb + (size_t)tok[rr] * 512;
            const float4 s0 = *(const float4*)(arow + k0 + q4 * 8);
            const float4 s1 = *(const float4*)(arow + k0 + q4 * 8 + 4);
            unsigned short tmp[8] = {f2bf(s0.x), f2bf(s0.y), f2bf(s0.z), f2bf(s0.w),
                                     f2bf(s1.x), f2bf(s1.y), f2bf(s1.z), f2bf(s1.w)};
            *(uint4*)(&As[row * 32 + q4 * 8]) = *(uint4*)tmp;
            const float4 t0 = *(const float4*)(Bm + (size_t)(n0 + row) * Bld + k0 + q4 * 8);
            const float4 t1 = *(const float4*)(Bm + (size_t)(n0 + row) * Bld + k0 + q4 * 8 + 4);
            unsigned short tb[8] = {f2bf(t0.x), f2bf(t0.y), f2bf(t0.z), f2bf(t0.w),
                                    f2bf(t1.x), f2bf(t1.y), f2bf(t1.z), f2bf(t1.w)};
            *(uint4*)(&Bs[row * 32 + q4 * 8]) = *(uint4*)tb;
        }
        __syncthreads();

        bf16x8 af[4], bfr[4];
#pragma unroll
        for (int i = 0; i < 4; i++)
            af[i] = *(const bf16x8*)(&As[(wm + 16 * i + l16) * 32 + quad * 8]);
#pragma unroll
        for (int j = 0; j < 4; j++)
            bfr[j] = *(const bf16x8*)(&Bs[(wn + 16 * j + l16) * 32 + quad * 8]);
#pragma unroll
        for (int i = 0; i < 4; i++)
#pragma unroll
            for (int j = 0; j < 4; j++)
                acc[i][j] = __builtin_amdgcn_mfma_f32_16x16x32_bf16(af[i], bfr[j], acc[i][j], 0, 0, 0);
    }

#pragma unroll
    for (int i = 0; i < 4; i++)
#pragma unroll
        for (int j = 0; j < 4; j++)
#pragma unroll
            for (int r = 0; r < 4; r++) {
                const int m = m0 + wm + 16 * i + quad * 4 + r;
                const int n = n0 + wn + 16 * j + l16;
                C[(size_t)m * Cld + n] = acc[i][j][r] + (bias ? bias[n] : 0.f);
            }
}

// ---------------------------------------------------------------------------
// Merged setup GEMM: 864 blocks.
//  bid   0..127 : ua partials  (split-K x2, 16x4 tiles)   Pua[kk] = enc·Ua_w^T
//  bid 128..223 : Gxe (emb-indirect A, 8x12 tiles, +b_ih) Gxe = Emb·W_ih[:,:512]^T
//  bid 224..607 : ENC2 partials (split-K x2, 16x12 tiles) Penc2[kk] = enc·W_ihc^T
//  bid 608..863 : h0 partials (r0-verified k_h0part body)
// ---------------------------------------------------------------------------
__global__ __launch_bounds__(256, 2)
void gemm_setup(const float* __restrict__ enc, const float* __restrict__ emb,
                const int* __restrict__ tgt,
                const float* __restrict__ Ua_w, const float* __restrict__ W_ih,
                const float* __restrict__ b_ih, const float* __restrict__ ehid,
                const float* __restrict__ Wh,
                float* __restrict__ Pua, float* __restrict__ Gxe,
                float* __restrict__ Penc2, float* __restrict__ h0p)
{
    const int bid = blockIdx.x;
    if (bid < 128) {
        const int kk = bid & 1, l = bid >> 1;        // 64 tiles
        const int mt = l & 15, nt = l >> 4;          // 16 x 4
        gemm_tile_f32(enc, 1024, Ua_w, 1024, nullptr,
                      Pua + (size_t)kk * 1048576, 512,
                      mt * 128, nt * 128, kk * 512, kk * 512 + 512);
    } else if (bid < 224) {
        const int l = bid - 128;                     // 96 tiles
        const int mt = l & 7, nt = l >> 3;           // 8 x 12
        gemm_tile_emb(emb, tgt, W_ih, 1536, b_ih,
                      Gxe, 1536, mt * 128, nt * 128);
    } else if (bid < 608) {
        int l = bid - 224;                           // 384 = 2 x 192 tiles
        const int kk = l & 1; l >>= 1;
        const int mt = l & 15, nt = l >> 4;          // 16 x 12
        gemm_tile_f32(enc, 1024, W_ih + 512, 1536, nullptr,
                      Penc2 + (size_t)kk * 3145728, 1536,
                      mt * 128, nt * 128, kk * 512, kk * 512 + 512);
    } else {
        // h0 partials (r0-verified k_h0part body)
        const int o = (bid - 608) * 256 + threadIdx.x;  // 65536
        const int b = o & 31, j = (o >> 5) & 511, c = o >> 14;
        const float* x = ehid + b * 1024 + c * 256;
        const float* w = Wh + (size_t)j * 1024 + c * 256;
        float s = 0.f;
#pragma unroll 8
        for (int k = 0; k < 256; k += 4)
            s += dot4(*(const float4*)(x + k), *(const float4*)(w + k));
        h0p[c * 16384 + b * 512 + j] = s;
    }
}

// Combine split-K partials (r7-verified) + h0 finalize (r0-verified body).
// 4160 blocks.
__global__ void k_combine(const float* __restrict__ Pua, const float* __restrict__ Ua_b,
                          float* __restrict__ ua, const float* __restrict__ Penc2,
                          float* __restrict__ ENC2, const float* __restrict__ h0p,
                          const float* __restrict__ bh, float* __restrict__ h)
{
    const int bid = blockIdx.x;
    if (bid < 4096) {
        const int o = bid * 256 + threadIdx.x;  // f4 units, 1,048,576 total
        if (o < 262144) {
            const float4 a = ((const float4*)Pua)[o];
            const float4 b = ((const float4*)Pua)[262144 + o];
            const float4 bi = *(const float4*)(Ua_b + (o & 127) * 4);
            float4 r; r.x = a.x + b.x + bi.x; r.y = a.y + b.y + bi.y;
            r.z = a.z + b.z + bi.z; r.w = a.w + b.w + bi.w;
            ((float4*)ua)[o] = r;
        } else {
            const int i = o - 262144;                   // 0..786431
            const float4 a = ((const float4*)Penc2)[i];
            const float4 b = ((const float4*)Penc2)[786432 + i];
            float4 r; r.x = a.x + b.x; r.y = a.y + b.y; r.z = a.z + b.z; r.w = a.w + b.w;
            ((float4*)ENC2)[i] = r;
        }
    } else {
        const int o = (bid - 4096) * 256 + threadIdx.x;  // 16384
        h[o] = bh[o & 511] + h0p[o] + h0p[16384 + o] + h0p[32768 + o] + h0p[49152 + o];
    }
}

// ---------------------------------------------------------------------------
// Logits GEMM (r6-verified): XCD-swizzled 1D grid; A bf16.
// ---------------------------------------------------------------------------
__global__ __launch_bounds__(256, 2)
void gemm_logits(const unsigned short* __restrict__ A16, const float* __restrict__ Bm,
                 const float* __restrict__ bias, float* __restrict__ C)
{
    const int bid = blockIdx.x;          // 0..2047
    const int xcd = bid & 7;
    const int l   = bid >> 3;            // 0..255
    const int nt  = (l >> 3) * 8 + xcd;  // 0..255
    if (nt >= 250) return;
    const int m0 = (l & 7) * 128;
    const int n0 = nt * 128;
    const int N = V_, K = 512, Bld = 512;

    __shared__ unsigned short As[128 * 32];
    __shared__ unsigned short Bs[128 * 32];

    const int tid  = threadIdx.x;
    const int lane = tid & 63;
    const int wave = tid >> 6;
    const int wm   = (wave & 1) * 64;
    const int wn   = (wave >> 1) * 64;
    const int quad = lane >> 4;
    const int l16  = lane & 15;

    f32x4 acc[4][4];
#pragma unroll
    for (int i = 0; i < 4; i++)
#pragma unroll
        for (int j = 0; j < 4; j++) acc[i][j] = (f32x4){0.f, 0.f, 0.f, 0.f};

    const int r0 = tid >> 2;
    const int q4 = tid & 3;

    for (int k0 = 0; k0 < K; k0 += 32) {
        __syncthreads();
#pragma unroll
        for (int rr = 0; rr < 2; rr++) {
            const int row = r0 + rr * 64;
            const uint4 v = *(const uint4*)(A16 + (size_t)(m0 + row) * K + k0 + q4 * 8);
            *(uint4*)(&As[row * 32 + q4 * 8]) = v;
            const float4 t0 = *(const float4*)(Bm + (size_t)(n0 + row) * Bld + k0 + q4 * 8);
            const float4 t1 = *(const float4*)(Bm + (size_t)(n0 + row) * Bld + k0 + q4 * 8 + 4);
            unsigned short tb[8] = {f2bf(t0.x), f2bf(t0.y), f2bf(t0.z), f2bf(t0.w),
                                    f2bf(t1.x), f2bf(t1.y), f2bf(t1.z), f2bf(t1.w)};
            *(uint4*)(&Bs[row * 32 + q4 * 8]) = *(uint4*)tb;
        }
        __syncthreads();

        bf16x8 af[4], bfr[4];
#pragma unroll
        for (int i = 0; i < 4; i++)
            af[i] = *(const bf16x8*)(&As[(wm + 16 * i + l16) * 32 + quad * 8]);
#pragma unroll
        for (int j = 0; j < 4; j++)
            bfr[j] = *(const bf16x8*)(&Bs[(wn + 16 * j + l16) * 32 + quad * 8]);
#pragma unroll
        for (int i = 0; i < 4; i++)
#pragma unroll
            for (int j = 0; j < 4; j++)
                acc[i][j] = __builtin_amdgcn_mfma_f32_16x16x32_bf16(af[i], bfr[j], acc[i][j], 0, 0, 0);
    }

#pragma unroll
    for (int i = 0; i < 4; i++)
#pragma unroll
        for (int j = 0; j < 4; j++)
#pragma unroll
            for (int r = 0; r < 4; r++) {
                const int m = m0 + wm + 16 * i + quad * 4 + r;
                const int n = n0 + wn + 16 * j + l16;
                C[(size_t)m * N + n] = acc[i][j][r] + bias[n];
            }
}

// ---------------------------------------------------------------------------
// Scan launch 1 (r6-verified): 512 blocks x 256 threads.
//  blocks 0..255 : qp partials — r0 k_q layout (b-lane broadcast of Wa_w)
//  blocks 256..511: ghp partials — r0 k_ggx gh-half layout
// ---------------------------------------------------------------------------
__global__ __launch_bounds__(256)
void k_q_gh(const float* __restrict__ h, const float* __restrict__ Wa_w,
            const float* __restrict__ W_hh,
            float* __restrict__ qp, float* __restrict__ ghp)
{
    const int bid = blockIdx.x;
    const int tid = threadIdx.x;
    if (bid < 256) {
        const int o = bid * 256 + tid;                        // 0..65535
        const int b = o & 31, j = (o >> 5) & 511, c = o >> 14;
        const float* x = h + b * 512 + c * 128;
        const float* w = Wa_w + (size_t)j * 512 + c * 128;
        float s = 0.f;
#pragma unroll 8
        for (int k = 0; k < 128; k += 4)
            s += dot4(*(const float4*)(x + k), *(const float4*)(w + k));
        qp[c * 16384 + b * 512 + j] = s;
    } else {
        const int o = (bid - 256) * 256 + tid;                // 0..65535
        const int b = o & 31, j = (o >> 5) & 511, c = o >> 14;
        const float* x  = h + b * 512 + c * 128;
        const float* w0 = W_hh + (size_t)j * 512 + c * 128;
        const float* w1 = w0 + 512 * 512;
        const float* w2 = w1 + 512 * 512;
        float s0 = 0.f, s1 = 0.f, s2 = 0.f;
#pragma unroll 8
        for (int k = 0; k < 128; k += 4) {
            const float4 xv = *(const float4*)(x + k);
            s0 += dot4(xv, *(const float4*)(w0 + k));
            s1 += dot4(xv, *(const float4*)(w1 + k));
            s2 += dot4(xv, *(const float4*)(w2 + k));
        }
        const int ix = b * 512 + j;
        ghp[(c * 3 + 0) * 16384 + ix] = s0;
        ghp[(c * 3 + 1) * 16384 + ix] = s1;
        ghp[(c * 3 + 2) * 16384 + ix] = s2;
    }
}

// ---------------------------------------------------------------------------
// Scan launch 2 (widened from the r6-verified 32-block version):
// 128 blocks x 256 threads; block = (b, part) with part in 0..3.
// q-sum / scores / softmax are computed redundantly per part (verbatim r6
// bodies; L2-hit reads, ~2 us). gx and GRU finalize are sliced: part owns
// j in [part*128, part*128+128) and the matching 3 gate-chunks of gx.
// ---------------------------------------------------------------------------
__global__ __launch_bounds__(256)
void k_attn_fin(const float* __restrict__ qp, const float* __restrict__ Wa_b,
                const float* __restrict__ ua, const float* __restrict__ Va_w,
                const float* __restrict__ Va_b, const float* __restrict__ ENC2,
                const float* __restrict__ ghp, const float* __restrict__ Gxe,
                const float* __restrict__ b_hh, float* __restrict__ h,
                unsigned short* __restrict__ Hall, float* __restrict__ attn_out,
                float* __restrict__ hf, int t)
{
    __shared__ float qs[512];
    __shared__ float parts[64][4];
    __shared__ float wsm[64];
    __shared__ float gxs[1536];

    const int bid = blockIdx.x;          // 0..127
    const int b = bid >> 2, part = bid & 3;
    const int tid = threadIdx.x;

    for (int i = tid; i < 512; i += 256) {
        const int ix = b * 512 + i;
        qs[i] = qp[ix] + qp[16384 + ix] + qp[32768 + ix] + qp[49152 + ix] + Wa_b[i];
    }
    __syncthreads();

    {
        const int s = tid >> 2, p = tid & 3;
        const float* uar = ua + ((size_t)(b * 64 + s)) * 512 + p * 128;
        const float* vp = Va_w + p * 128;
        float acc = 0.f;
#pragma unroll 8
        for (int k = 0; k < 128; k += 4) {
            float4 u4 = *(const float4*)(uar + k);
            float4 v4 = *(const float4*)(vp + k);
            float4 q4 = *(const float4*)(&qs[p * 128 + k]);
            acc += v4.x * tanh_fast(q4.x + u4.x) + v4.y * tanh_fast(q4.y + u4.y)
                 + v4.z * tanh_fast(q4.z + u4.z) + v4.w * tanh_fast(q4.w + u4.w);
        }
        parts[s][p] = acc;
    }
    __syncthreads();

    if (tid < 64) {
        float sc = parts[tid][0] + parts[tid][1] + parts[tid][2] + parts[tid][3] + Va_b[0];
        float mx = sc;
        for (int off = 32; off; off >>= 1) mx = fmaxf(mx, __shfl_down(mx, off));
        mx = __shfl(mx, 0);
        float e = __expf(sc - mx);
        float sum = e;
        for (int off = 32; off; off >>= 1) sum += __shfl_down(sum, off);
        sum = __shfl(sum, 0);
        float w = e / sum;
        wsm[tid] = w;
        if (part == 0) attn_out[((size_t)b * T_ + t) * 64 + tid] = w;
    }
    __syncthreads();

    // gx slice: 96 threads -> 3 gate-chunks of 32 f4-columns each
    if (tid < 96) {
        const int g = tid >> 5, u = tid & 31;
        const int i4 = g * 128 + part * 32 + u;      // f4-column in [0,384)
        float4 a = {0.f, 0.f, 0.f, 0.f};
        const float* eb = ENC2 + ((size_t)b * 64) * 1536 + i4 * 4;
        for (int s2 = 0; s2 < 64; s2++) {
            const float w = wsm[s2];
            const float4 e4 = *(const float4*)(eb + (size_t)s2 * 1536);
            a.x += w * e4.x; a.y += w * e4.y; a.z += w * e4.z; a.w += w * e4.w;
        }
        *(float4*)(&gxs[i4 * 4]) = a;
    }
    __syncthreads();

    // finalize slice: j in [part*128, part*128+128)
    if (tid < 128) {
        const int j = part * 128 + tid;
        const int o2 = b * 512 + j;
        float gh0 = b_hh[j], gh1 = b_hh[512 + j], gh2 = b_hh[1024 + j];
#pragma unroll
        for (int c2 = 0; c2 < 4; c2++) {
            gh0 += ghp[(c2 * 3 + 0) * 16384 + o2];
            gh1 += ghp[(c2 * 3 + 1) * 16384 + o2];
            gh2 += ghp[(c2 * 3 + 2) * 16384 + o2];
        }
        const float* gxe = Gxe + ((size_t)(b * T_ + t)) * 1536;
        const float gx0 = gxs[j] + gxe[j];
        const float gx1 = gxs[512 + j] + gxe[512 + j];
        const float gx2 = gxs[1024 + j] + gxe[1024 + j];
        const float r = sigmoid_fast(gx0 + gh0);
        const float z = sigmoid_fast(gx1 + gh1);
        const float n = tanh_fast(gx2 + r * gh2);
        const float hn = (1.f - z) * n + z * h[o2];
        h[o2] = hn;
        Hall[((size_t)b * T_ + t) * 512 + j] = f2bf(hn);
        if (t == T_ - 1) hf[o2] = hn;
    }
}

// ---------------------------------------------------------------------------
// Online log_softmax over V=32000 per row, in place. (r0-verified)
// ---------------------------------------------------------------------------
__global__ void k_logsoftmax(float* __restrict__ logits)
{
    __shared__ float rm[4], rs[4];
    const int row = blockIdx.x;
    float* p = logits + (size_t)row * V_;
    const int tid = threadIdx.x;

    float m = -1e30f, s = 0.f;
    for (int i = tid * 4; i < V_; i += 1024) {
        const float4 x = *(const float4*)(p + i);
        const float m4 = fmaxf(fmaxf(x.x, x.y), fmaxf(x.z, x.w));
        const float mn = fmaxf(m, m4);
        s = s * __expf(m - mn) + __expf(x.x - mn) + __expf(x.y - mn)
          + __expf(x.z - mn) + __expf(x.w - mn);
        m = mn;
    }
    for (int off = 32; off; off >>= 1) {
        const float m2 = __shfl_down(m, off), s2 = __shfl_down(s, off);
        const float mn = fmaxf(m, m2);
        s = s * __expf(m - mn) + s2 * __expf(m2 - mn);
        m = mn;
    }
    if ((tid & 63) == 0) { rm[tid >> 6] = m; rs[tid >> 6] = s; }
    __syncthreads();
    const float M = fmaxf(fmaxf(rm[0], rm[1]), fmaxf(rm[2], rm[3]));
    const float S = rs[0] * __expf(rm[0] - M) + rs[1] * __expf(rm[1] - M)
                  + rs[2] * __expf(rm[2] - M) + rs[3] * __expf(rm[3] - M);
    const float lse = M + __logf(S);

    for (int i = tid * 4; i < V_; i += 1024) {
        float4 x = *(const float4*)(p + i);
        x.x -= lse; x.y -= lse; x.z -= lse; x.w -= lse;
        *(float4*)(p + i) = x;
    }
}

// ---------------------------------------------------------------------------
extern "C" void kernel_launch(void* const* d_in, const int* in_sizes, int n_in,
                              void* d_out, int out_size, void* d_ws, size_t ws_size,
                              hipStream_t stream)
{
    const float* enc   = (const float*)d_in[0];   // [B,S,2H]
    const float* ehid  = (const float*)d_in[1];   // [1,B,2H]
    const int*   tgt   = (const int*)d_in[2];     // [B,T]
    const float* emb   = (const float*)d_in[3];   // [V,H]
    const float* Wa_w  = (const float*)d_in[4];   // [H,H]
    const float* Wa_b  = (const float*)d_in[5];
    const float* Ua_w  = (const float*)d_in[6];   // [H,2H]
    const float* Ua_b  = (const float*)d_in[7];
    const float* Va_w  = (const float*)d_in[8];   // [1,H]
    const float* Va_b  = (const float*)d_in[9];   // [1]
    const float* W_ih  = (const float*)d_in[10];  // [3H,3H]
    const float* b_ih  = (const float*)d_in[11];
    const float* W_hh  = (const float*)d_in[12];  // [3H,H]
    const float* b_hh  = (const float*)d_in[13];
    const float* Wh    = (const float*)d_in[14];  // [H,2H]
    const float* bh    = (const float*)d_in[15];
    const float* out_w = (const float*)d_in[16];  // [V,H]
    const float* out_b = (const float*)d_in[17];  // [V]

    float* outp = (float*)d_out;
    float* lp   = outp;                 // [B,T,V] = 32,768,000 floats
    float* hf   = outp + 32768000;      // [1,B,H]
    float* attn = outp + 32784384;      // [B,T,S]

    // Transient scratch inside the lp region (all dead before gemm_logits
    // overwrites lp):
    float* Gxe   = lp;                  // 1,572,864   [B*T, 3H]  emb-part + b_ih
    float* ghp   = lp + 2097152;        //   196,608   12 x [B*H]
    float* qp    = lp + 2293760;        //    65,536   4 x [B*H]
    float* ENC2  = lp + 2359296;        // 3,145,728   [B*S, 3H]  enc @ W_ihc^T
    float* h0p   = lp + 5505024;        //    65,536   setup-only
    float* Pua   = lp + 5570560;        // 2,097,152   ua split-K partials
    float* Penc2 = lp + 7667712;        // 6,291,456   ENC2 split-K partials

    // Persistent ws (same layout as verified r0)
    float* ws  = (float*)d_ws;
    float* h   = ws;                    // 16,384
    float* ua  = ws + 49152;            // 1,048,576  [B*S, H]
    unsigned short* Hall = (unsigned short*)(ws + 1097728);  // [B*T, H] bf16

    // ---- setup: 2 launches ----
    gemm_setup<<<864, 256, 0, stream>>>(enc, emb, tgt, Ua_w, W_ih, b_ih,
                                        ehid, Wh, Pua, Gxe, Penc2, h0p);
    k_combine<<<4160, 256, 0, stream>>>(Pua, Ua_b, ua, Penc2, ENC2,
                                        h0p, bh, h);

    // ---- sequential scan: r6-verified 2-launch-per-step loop ----
    for (int t = 0; t < T_; t++) {
        k_q_gh<<<512, 256, 0, stream>>>(h, Wa_w, W_hh, qp, ghp);
        k_attn_fin<<<128, 256, 0, stream>>>(qp, Wa_b, ua, Va_w, Va_b, ENC2,
                                            ghp, Gxe, b_hh, h, Hall, attn,
                                            hf, t);
    }

    // ---- logits + log_softmax ----
    gemm_logits<<<2048, 256, 0, stream>>>(Hall, out_w, out_b, lp);
    k_logsoftmax<<<1024, 256, 0, stream>>>(lp);
}